// Round 11
// baseline (151.469 us; speedup 1.0000x reference)
//
#include <hip/hip_runtime.h>

// SSIM (B=16, C=3, H=W=512, fp32) -> scalar mean.
// v17: v16 + 4-col/1-row horizontal ownership + separable x1.25 swizzle.
//  - v16 post-mortem (50 us): DS-pipe ~27 us + VALU ~25.5 us ~= measured 50
//    -> pipes not overlapping; DS is the bigger term. Cut DS insts.
//  - Horizontal: threads 0-127 own row 0, 128-255 row 1; 4 cols each.
//    Taps for 4 consecutive cols span 14 elements -> 14 ds_read_b128 +
//    4 ds_write_b128 = 18 DS insts/step (v16: 28). Same 44 vfma4.
//  - Swizzle byte(E) = 16E + 16*(E>>2): for E = 4q+K this is EXACTLY
//    80q + (16K + 16*(K>>2)) -> one vaddr + uniform immediates.
//    Read start-banks 20q mod 32 for q=0..7: {0,20,8,28,16,4,24,12} --
//    spans tile all 32 banks: conflict-free (enumerated). Writes worst
//    2-way on 4 insts/step: negligible. Inflation 1.25x -> 20.9 KB LDS.
//  - Ring + pend prefetch + #pragma unroll 1 + (256,6): v16-proven no-spill.
//  - Falsifiers: conflicts >1M -> bank model wrong; WRITE_SIZE >10MB -> spill.

typedef float v2f __attribute__((ext_vector_type(2)));
typedef float v4f __attribute__((ext_vector_type(4)));

#define IMG_H 512
#define IMG_W 512
#define N_IMG 48                    // B*C
#define WS 11
#define PAD 5
#define CHUNK 16                    // output rows per block
#define NCHUNK (IMG_H / CHUNK)      // 32
#define RING 12                     // rows held in registers
#define REG_B 10464                 // bytes per row-region (max swz byte 10448)
#define INV_NPX (1.0f / (48.0f * 512.0f * 512.0f))

__device__ __forceinline__ v2f vfma2(v2f a, v2f b, v2f c) {
    return __builtin_elementwise_fma(a, b, c);
}
__device__ __forceinline__ v4f vfma4(v4f a, v4f b, v4f c) {
    return __builtin_elementwise_fma(a, b, c);
}
__device__ __forceinline__ float uni(float x) {   // force wave-uniform -> SGPR
    return __int_as_float(__builtin_amdgcn_readfirstlane(__float_as_int(x)));
}
// swizzled byte offset of 16B element E: 16*E + 16*(E>>2)
__device__ __forceinline__ unsigned swz16(int E) {
    return (unsigned)((E + (E >> 2)) * 16);
}

__global__ __launch_bounds__(256, 6) void ssim_partial_kernel(
    const float* __restrict__ img1,
    const float* __restrict__ img2,
    const float* __restrict__ window,
    float* __restrict__ out)
{
    __shared__ __align__(16) char lds[2 * REG_B];   // 20928 B
    __shared__ float wred[4];

    const int tid  = threadIdx.x;
    const int bc   = blockIdx.x;             // image*channel 0..47
    const int r0   = blockIdx.y * CHUNK;
    const int c0   = tid * 2;                // vertical ownership: cols c0,c0+1
    const int qrow = tid >> 7;               // horizontal: output row 0/1
    const int q    = tid & 127;              // horizontal: col quad 4q..4q+3

    // 1-D gaussian from window row 5 (w2d[5][j] = g5*g[j]); hoist to SGPRs.
    float g[WS];
    {
        const float g5  = sqrtf(window[5 * WS + 5]);
        const float inv = 1.0f / g5;
#pragma unroll
        for (int j = 0; j < WS; ++j) g[j] = uni(window[5 * WS + j] * inv);
    }
    const float C1v = 0.01f * 0.01f;
    const float C2v = 0.03f * 0.03f;

    const float* __restrict__ p1 = img1 + (size_t)bc * (IMG_H * IMG_W);
    const float* __restrict__ p2 = img2 + (size_t)bc * (IMG_H * IMG_W);

    // zero halo: E in {0..5, 518..523} per row-region (24 stores)
    if (tid < 24) {
        const int rg = tid / 12, h = tid % 12;
        const int E  = (h < 6) ? h : (512 + h);
        *(v4f*)(lds + rg * REG_B + swz16(E)) = (v4f)(0.0f);
    }
    __syncthreads();

    // step-invariant LDS addressing
    char*       wA = lds + swz16(c0 + 6);          // write col c0   (+k*REG_B imm)
    char*       wB = lds + swz16(c0 + 7);          // write col c0+1 (+k*REG_B imm)
    const char* rd = lds + qrow * REG_B + 80 * q;  // reads: + 16K+16*(K>>2) imm

    // register ring: slot i holds row R-5+i at step base R
    v2f rx1[RING], rx2[RING];
#pragma unroll
    for (int i = 0; i < RING; ++i) { rx1[i] = (v2f)(0.0f); rx2[i] = (v2f)(0.0f); }

    // warm-up: slots 2..11 <- rows r0-5 .. r0+4
#pragma unroll
    for (int i = 0; i < 10; ++i) {
        const int rr = r0 - PAD + i;
        v2f u1 = (v2f)(0.0f), u2 = (v2f)(0.0f);
        if (rr >= 0 && rr < IMG_H) {               // uniform branch
            u1 = *(const v2f*)(p1 + rr * IMG_W + c0);
            u2 = *(const v2f*)(p2 + rr * IMG_W + c0);
        }
        rx1[2 + i] = u1; rx2[2 + i] = u2;
    }
    // prefetch rows r0+5, r0+6 (consumed at step 0)
    v2f pend1[2], pend2[2];
#pragma unroll
    for (int j = 0; j < 2; ++j) {
        const int rr = r0 + PAD + j;
        v2f u1 = (v2f)(0.0f), u2 = (v2f)(0.0f);
        if (rr < IMG_H) {
            u1 = *(const v2f*)(p1 + rr * IMG_W + c0);
            u2 = *(const v2f*)(p2 + rr * IMG_W + c0);
        }
        pend1[j] = u1; pend2[j] = u2;
    }

    float acc = 0.0f;

#pragma unroll 1
    for (int step = 0; step < CHUNK / 2; ++step) {
        const int R = r0 + step * 2;           // output rows R, R+1

        // shift ring by 2; retire pend into slots 10,11
#pragma unroll
        for (int i = 0; i < RING - 2; ++i) { rx1[i] = rx1[i + 2]; rx2[i] = rx2[i + 2]; }
        rx1[10] = pend1[0]; rx2[10] = pend2[0];
        rx1[11] = pend1[1]; rx2[11] = pend2[1];

        // issue NEXT step's loads now (rows R+7, R+8); consumed next step
        if (step + 1 < CHUNK / 2) {            // uniform branch
#pragma unroll
            for (int j = 0; j < 2; ++j) {
                const int rr = R + 7 + j;      // (R+2) + PAD + j
                v2f u1 = (v2f)(0.0f), u2 = (v2f)(0.0f);
                if (rr < IMG_H) {              // uniform branch
                    u1 = *(const v2f*)(p1 + rr * IMG_W + c0);
                    u2 = *(const v2f*)(p2 + rr * IMG_W + c0);
                }
                pend1[j] = u1; pend2[j] = u2;
            }
        }

        // ---- vertical pass A: mu1, mu2, rows k=0,1 (v2f over col pair) ----
        v2f a0[2] = {(v2f)(0.0f), (v2f)(0.0f)};
        v2f a1[2] = {(v2f)(0.0f), (v2f)(0.0f)};
#pragma unroll
        for (int k = 0; k < 2; ++k)
#pragma unroll
            for (int i = 0; i < WS; ++i) {
                const v2f w = (v2f)(g[i]);
                a0[k] = vfma2(w, rx1[i + k], a0[k]);
                a1[k] = vfma2(w, rx2[i + k], a1[k]);
            }
        // ---- vertical pass B: S = x1^2+x2^2, P = x1*x2 ----
        v2f b0[2] = {(v2f)(0.0f), (v2f)(0.0f)};
        v2f b1[2] = {(v2f)(0.0f), (v2f)(0.0f)};
#pragma unroll
        for (int u = 0; u < RING; ++u) {
            const v2f X1 = rx1[u], X2 = rx2[u];
            const v2f S = vfma2(X1, X1, X2 * X2);
            const v2f P = X1 * X2;
            if (u <= 10) {                          // k=0 tap i=u
                b0[0] = vfma2((v2f)(g[u]), S, b0[0]);
                b1[0] = vfma2((v2f)(g[u]), P, b1[0]);
            }
            if (u >= 1) {                           // k=1 tap i=u-1
                b0[1] = vfma2((v2f)(g[u - 1]), S, b0[1]);
                b1[1] = vfma2((v2f)(g[u - 1]), P, b1[1]);
            }
        }
        // repack -> v4f {mu1,mu2,S,P} per (col,row); store to region k
#pragma unroll
        for (int k = 0; k < 2; ++k) {
            const v4f w0 = (v4f){a0[k].x, a1[k].x, b0[k].x, b1[k].x};
            const v4f w1 = (v4f){a0[k].y, a1[k].y, b0[k].y, b1[k].y};
            *(v4f*)(wA + k * REG_B) = w0;
            *(v4f*)(wB + k * REG_B) = w1;
        }
        __syncthreads();

        // ---- horizontal conv + SSIM: row qrow, cols 4q..4q+3 ----
        // element K = m+1 at imm 16K+16*(K>>2); output col 4q+d uses tap
        // i = m-d on element m (valid 0<=i<=10). 14 reads, 44 vfma4.
        {
            v4f h[4] = {(v4f)(0.0f), (v4f)(0.0f), (v4f)(0.0f), (v4f)(0.0f)};
#pragma unroll
            for (int m = 0; m < 14; ++m) {
                const int K = m + 1;
                const v4f t = *(const v4f*)(rd + (16 * K + 16 * (K >> 2)));
#pragma unroll
                for (int d = 0; d < 4; ++d) {
                    const int i = m - d;
                    if (i >= 0 && i <= 10) h[d] = vfma4((v4f)(g[i]), t, h[d]);
                }
            }
#pragma unroll
            for (int d = 0; d < 4; ++d) {
                const float mu1 = h[d].x, mu2 = h[d].y;
                const float mu1s = mu1 * mu1;
                const float mu2s = mu2 * mu2;
                const float mu12 = mu1 * mu2;
                const float sgs  = h[d].z - mu1s - mu2s;   // sigma1^2+sigma2^2
                const float sg12 = h[d].w - mu12;
                const float num  = (2.f * mu12 + C1v) * (2.f * sg12 + C2v);
                const float den  = (mu1s + mu2s + C1v) * (sgs + C2v);
                float r = __builtin_amdgcn_rcpf(den);
                r = r * fmaf(-den, r, 2.0f);               // Newton -> ~1 ulp
                acc = fmaf(num, r, acc);
            }
        }
        __syncthreads();                                   // before LDS overwrite
    }

    // block reduction -> single atomic per block (pre-scaled by 1/Npx)
#pragma unroll
    for (int off = 32; off > 0; off >>= 1)
        acc += __shfl_down(acc, off);
    if ((tid & 63) == 0) wred[tid >> 6] = acc;
    __syncthreads();
    if (tid == 0) {
        const float s = (wred[0] + wred[1]) + (wred[2] + wred[3]);
        atomicAdd(out, s * INV_NPX);
    }
}

extern "C" void kernel_launch(void* const* d_in, const int* in_sizes, int n_in,
                              void* d_out, int out_size, void* d_ws, size_t ws_size,
                              hipStream_t stream) {
    const float* img1   = (const float*)d_in[0];
    const float* img2   = (const float*)d_in[1];
    const float* window = (const float*)d_in[2];
    float* out = (float*)d_out;

    hipMemsetAsync(out, 0, sizeof(float), stream);   // graph-capturable
    dim3 grid(N_IMG, NCHUNK);
    ssim_partial_kernel<<<grid, 256, 0, stream>>>(img1, img2, window, out);
}